// Round 9
// baseline (163.468 us; speedup 1.0000x reference)
//
#include <hip/hip_runtime.h>

// WeightedAggEdge: node_feat = h@Wn^T; per-edge segment-softmax attention
// over fc_e(e) grouped by src node; outputs (node_feat, gamma * e_w).
//
// Round 9: (1) per-XCD denom replicas (blockIdx&7) -> atomics stay XCD-local,
// kred sums 8 replicas; (2) transposed MFMA (swap A/B args, identical loads)
// so epilogues store float4 instead of scalars (k1, k4).

constexpr int kNodes   = 50000;
constexpr int kEdges   = 800000;
constexpr int kNodeIn  = 128;
constexpr int kNodeOut = 64;
constexpr int kEdgeIn  = 64;
constexpr int kEdgeOut = 64;
constexpr int kNodesP  = 50016;   // replica stride
#define NEG_SLOPE 0.01f

typedef __attribute__((ext_vector_type(8))) short short8;   // 8 bf16 = 4 VGPRs
typedef __attribute__((ext_vector_type(4))) short short4v;  // 4 bf16 = 8 B
typedef __attribute__((ext_vector_type(4))) float f32x4;

// ws layout (float index):
//   [0, 64)                    v = We^T @ Wa_e
//   [64, 50064)                s_n
//   [50064, 100064)            denom (final, written by kred)
//   [100064, 500192)           rep: 8 x kNodesP replica accumulators
//   [500192, 1300192)          ex
//   [1300192, 1302240)         We_bf16 (4096 shorts)
//   [1302240, 1306336)         Wn_bf16 (8192 shorts)
//   [1306368, +25.6M)          e_bf16 (kEdges*64 shorts)
constexpr int kOffV     = 0;
constexpr int kOffSn    = 64;
constexpr int kOffDenom = 50064;
constexpr int kOffRep   = 100064;
constexpr int kOffEx    = 500192;
constexpr int kOffWeB   = 1300192;
constexpr int kOffWnB   = 1302240;
constexpr int kOffEbf   = 1306368;
constexpr int kRepTotal = 8 * kNodesP;   // 400128

__device__ inline short f2bf(float x) {
    union { float f; unsigned u; } v; v.f = x;
    unsigned r = v.u + 0x7FFFu + ((v.u >> 16) & 1u);  // RNE
    return (short)(r >> 16);
}

// 48 blocks: 0..15 convert We (4096), 16..47 convert Wn (8192); block 0 also v.
__global__ void k0_prep(const float* __restrict__ We, const float* __restrict__ Wn,
                        const float* __restrict__ Wa,
                        float* __restrict__ v, short* __restrict__ Web,
                        short* __restrict__ Wnb) {
    int b = blockIdx.x, t = threadIdx.x;
    if (b == 0 && t < kEdgeIn) {
        float acc = 0.f;
        #pragma unroll
        for (int c = 0; c < kEdgeOut; ++c) acc = fmaf(Wa[c], We[c * kEdgeIn + t], acc);
        v[t] = acc;
    }
    if (b < 16) {
        int i = b * 256 + t;
        Web[i] = f2bf(We[i]);
    } else {
        int i = (b - 16) * 256 + t;
        Wnb[i] = f2bf(Wn[i]);
    }
}

// node_feat^T-computed = Wn-tile x h-row via bf16 MFMA; one wave = 16 nodes.
// D'[channel][node]: lane l15 = node, reg = 4 consecutive channels -> f32x4 store.
// Also: s_n[n] = dot(Wa[64:128], node_feat[n]) via xor16/32 reduce; rep zero-init.
__global__ __launch_bounds__(256) void k1_mfma(
    const float* __restrict__ h, const short* __restrict__ Wnb,
    const float* __restrict__ Wa, float* __restrict__ node_feat,
    float* __restrict__ s_n, float* __restrict__ rep) {
    const int lane = threadIdx.x & 63;
    const int l15  = lane & 15;
    const int lhi  = lane >> 4;
    const int n0   = blockIdx.x * 64 + (threadIdx.x >> 6) * 16;

    int gid = blockIdx.x * 256 + threadIdx.x;       // 200192 threads total
    if (gid < kRepTotal) rep[gid] = 0.f;
    int g2 = gid + 200192;
    if (g2 < kRepTotal) rep[g2] = 0.f;

    // A-fragments (Wn rows): lane row = ct*16+l15 (tile-local l15), k = kt*32+lhi*8
    short8 Af[4][4];
    #pragma unroll
    for (int kt = 0; kt < 4; ++kt)
        #pragma unroll
        for (int ct = 0; ct < 4; ++ct)
            Af[kt][ct] = *reinterpret_cast<const short8*>(
                Wnb + (ct * 16 + l15) * kNodeIn + kt * 32 + lhi * 8);

    const int  arow   = n0 + l15;
    const bool rv     = arow < kNodes;
    const float* hrow = h + (size_t)arow * kNodeIn;

    f32x4 acc[4];
    #pragma unroll
    for (int ct = 0; ct < 4; ++ct) acc[ct] = (f32x4)(0.f);

    #pragma unroll
    for (int kt = 0; kt < 4; ++kt) {
        short8 bf;  // B: col = node l15, k slice
        if (rv) {
            f32x4 t0 = __builtin_nontemporal_load(
                reinterpret_cast<const f32x4*>(hrow + kt * 32 + lhi * 8));
            f32x4 t1 = __builtin_nontemporal_load(
                reinterpret_cast<const f32x4*>(hrow + kt * 32 + lhi * 8 + 4));
            bf[0] = f2bf(t0[0]); bf[1] = f2bf(t0[1]); bf[2] = f2bf(t0[2]); bf[3] = f2bf(t0[3]);
            bf[4] = f2bf(t1[0]); bf[5] = f2bf(t1[1]); bf[6] = f2bf(t1[2]); bf[7] = f2bf(t1[3]);
        } else {
            #pragma unroll
            for (int j = 0; j < 8; ++j) bf[j] = 0;
        }
        #pragma unroll
        for (int ct = 0; ct < 4; ++ct)
            acc[ct] = __builtin_amdgcn_mfma_f32_16x16x32_bf16(Af[kt][ct], bf, acc[ct], 0, 0, 0);
    }

    // Epilogue: lane owns node (n0+l15), channels ct*16 + lhi*4 + 0..3.
    float part = 0.f;
    #pragma unroll
    for (int ct = 0; ct < 4; ++ct) {
        f32x4 wa4 = *reinterpret_cast<const f32x4*>(Wa + 64 + ct * 16 + lhi * 4);
        part = fmaf(wa4[0], acc[ct][0], part);
        part = fmaf(wa4[1], acc[ct][1], part);
        part = fmaf(wa4[2], acc[ct][2], part);
        part = fmaf(wa4[3], acc[ct][3], part);
        if (rv)
            __builtin_nontemporal_store(acc[ct],
                reinterpret_cast<f32x4*>(node_feat + (size_t)arow * kNodeOut + ct * 16 + lhi * 4));
    }
    part += __shfl_xor(part, 16, 64);
    part += __shfl_xor(part, 32, 64);
    if (rv && lhi == 0) s_n[arow] = part;
}

// Coalesced streaming pass over e: 64 rows per block (4 iters x 16 rows).
// Thread t handles float4 #(t&15) of row; shfl-reduce dot; lane q==0 finishes
// the logit and atomically adds into this block's XCD-local replica.
__global__ __launch_bounds__(256) void kconv(
    const float* __restrict__ e, const float* __restrict__ v,
    const int* __restrict__ src, const float* __restrict__ s_n,
    float* __restrict__ rep, float* __restrict__ ex,
    short* __restrict__ ebf) {
    const int t   = threadIdx.x;
    const int q   = t & 15;
    const int rlo = t >> 4;
    const long base = (long)blockIdx.x * 64;
    float* myrep = rep + (blockIdx.x & 7) * kNodesP;

    f32x4 vv = *(reinterpret_cast<const f32x4*>(v) + q);

    #pragma unroll
    for (int it = 0; it < 4; ++it) {
        long r = base + it * 16 + rlo;
        f32x4 d = __builtin_nontemporal_load(
            reinterpret_cast<const f32x4*>(e + r * kEdgeIn) + q);
        float part = d[0] * vv[0] + d[1] * vv[1] + d[2] * vv[2] + d[3] * vv[3];
        part += __shfl_xor(part, 1, 64);
        part += __shfl_xor(part, 2, 64);
        part += __shfl_xor(part, 4, 64);
        part += __shfl_xor(part, 8, 64);
        short4v o;
        o[0] = f2bf(d[0]); o[1] = f2bf(d[1]); o[2] = f2bf(d[2]); o[3] = f2bf(d[3]);
        *reinterpret_cast<short4v*>(ebf + r * kEdgeIn + q * 4) = o;
        if (q == 0) {
            int s = src[r];
            float a = part + s_n[s];
            float lr = (a >= 0.f) ? a : NEG_SLOPE * a;
            float xe = __expf(lr);
            ex[r] = xe;
            atomicAdd(myrep + s, xe);
        }
    }
}

// denom[i] = sum of 8 replicas.
__global__ __launch_bounds__(256) void kred(
    const float* __restrict__ rep, float* __restrict__ denom) {
    int i = blockIdx.x * 256 + threadIdx.x;
    if (i >= kNodes) return;
    float s = 0.f;
    #pragma unroll
    for (int x = 0; x < 8; ++x) s += rep[x * kNodesP + i];
    denom[i] = s;
}

// e_weighted^T-computed: D'[channel][edge] via swapped-arg MFMA; f32x4 stores.
__global__ __launch_bounds__(256) void k4_mfma(
    const short* __restrict__ ebf, const short* __restrict__ Web,
    const int* __restrict__ src, const float* __restrict__ denom,
    const float* __restrict__ ex, float* __restrict__ oute) {
    const int wave = threadIdx.x >> 6;
    const int lane = threadIdx.x & 63;
    const int l15  = lane & 15;
    const int lhi  = lane >> 4;
    const long base = (long)blockIdx.x * 256 + wave * 64;  // first edge row

    // A-fragments (We rows): row = ct*16+l15 tile-local, k = kt*32+lhi*8
    short8 Af[2][4];
    #pragma unroll
    for (int kt = 0; kt < 2; ++kt)
        #pragma unroll
        for (int ct = 0; ct < 4; ++ct)
            Af[kt][ct] = *reinterpret_cast<const short8*>(
                Web + (ct * 16 + l15) * kEdgeIn + kt * 32 + lhi * 8);

    f32x4 acc[4][4];
    #pragma unroll
    for (int m = 0; m < 4; ++m)
        #pragma unroll
        for (int n = 0; n < 4; ++n) acc[m][n] = (f32x4)(0.f);

    #pragma unroll
    for (int m = 0; m < 4; ++m) {
        const short* erow = ebf + (base + m * 16 + l15) * kEdgeIn;
        #pragma unroll
        for (int kt = 0; kt < 2; ++kt) {
            short8 bf = *reinterpret_cast<const short8*>(erow + kt * 32 + lhi * 8);
            #pragma unroll
            for (int ct = 0; ct < 4; ++ct)
                acc[m][ct] = __builtin_amdgcn_mfma_f32_16x16x32_bf16(
                    Af[kt][ct], bf, acc[m][ct], 0, 0, 0);
        }
    }

    // Epilogue: lane owns edge (base+m*16+l15), channels ct*16+lhi*4+0..3.
    #pragma unroll
    for (int m = 0; m < 4; ++m) {
        const long edge = base + m * 16 + l15;
        int s = src[edge];
        float g = ex[edge] * __builtin_amdgcn_rcpf(denom[s]);
        #pragma unroll
        for (int ct = 0; ct < 4; ++ct) {
            f32x4 o = acc[m][ct] * g;
            __builtin_nontemporal_store(o,
                reinterpret_cast<f32x4*>(oute + edge * kEdgeOut + ct * 16 + lhi * 4));
        }
    }
}

extern "C" void kernel_launch(void* const* d_in, const int* in_sizes, int n_in,
                              void* d_out, int out_size, void* d_ws, size_t ws_size,
                              hipStream_t stream) {
    const float* h   = (const float*)d_in[0];
    const float* e   = (const float*)d_in[1];
    const float* Wn  = (const float*)d_in[2];
    const float* We  = (const float*)d_in[3];
    const float* Wa  = (const float*)d_in[4];
    const int*   src = (const int*)d_in[5];

    float* node_feat = (float*)d_out;
    float* oute      = (float*)d_out + (size_t)kNodes * kNodeOut;

    float* ws    = (float*)d_ws;
    float* v     = ws + kOffV;
    float* s_n   = ws + kOffSn;
    float* denom = ws + kOffDenom;
    float* rep   = ws + kOffRep;
    float* ex    = ws + kOffEx;
    short* Web   = (short*)(ws + kOffWeB);
    short* Wnb   = (short*)(ws + kOffWnB);
    short* ebf   = (short*)(ws + kOffEbf);

    k0_prep<<<48, 256, 0, stream>>>(We, Wn, Wa, v, Web, Wnb);
    k1_mfma<<<(kNodes + 63) / 64, 256, 0, stream>>>(h, Wnb, Wa, node_feat, s_n, rep);
    kconv<<<kEdges / 64, 256, 0, stream>>>(e, v, src, s_n, rep, ex, ebf);
    kred<<<(kNodes + 255) / 256, 256, 0, stream>>>(rep, denom);
    k4_mfma<<<kEdges / 256, 256, 0, stream>>>(ebf, Web, src, denom, ex, oute);
}